// Round 5
// baseline (144.483 us; speedup 1.0000x reference)
//
#include <hip/hip_runtime.h>
#include <math.h>
#include <stdint.h>

#define N_TRIAL 1000000
#define N_REF 8
#define N_DIM 16
#define BETA 1.0f
#define GAMMA 0.001f
// N_SELECT = {1,2,3,1} packed as nibbles
#define N_SELECT_PACKED 0x1321

#define WPB 4          // waves per block
#define D2_STRIDE 72   // 64+8: writes (16s+q)%32 and reads (8r+lane)%32 both 2-way = free

typedef float v4f  __attribute__((ext_vector_type(4)));
typedef int   v4iu __attribute__((ext_vector_type(4), aligned(4)));  // dword-aligned int4

// Full 4-lane-quad sum via two DPP quad_perm butterfly adds (VALU pipe, no
// lgkmcnt). Neutral vs ds_swizzle in round 2 but cheaper on the LDS pipe; kept.
//   0xB1 = quad_perm[1,0,3,2] (lane ^ 1),  0x4E = quad_perm[2,3,0,1] (lane ^ 2)
__device__ __forceinline__ float quad_sum(float x) {
    int   x0 = __builtin_bit_cast(int, x);
    float a  = __builtin_bit_cast(float,
               __builtin_amdgcn_update_dpp(0, x0, 0xB1, 0xF, 0xF, true));
    float y  = x + a;
    int   y0 = __builtin_bit_cast(int, y);
    float b  = __builtin_bit_cast(float,
               __builtin_amdgcn_update_dpp(0, y0, 0x4E, 0xF, 0xF, true));
    return y + b;
}

// Issue one scattered embed-row gather WITHOUT letting the scheduler
// re-serialize it (round-4 lesson: source-level batching was undone; VGPR
// stayed 36). volatile asm = program-ordered among themselves.
#define ISSUE_GATHER(dst, rowptr)                                        \
    asm volatile("global_load_dwordx4 %0, %1, off"                       \
                 : "=v"(dst)                                             \
                 : "v"((unsigned long long)(uintptr_t)(rowptr)))

// Per-wave, barrier-free two-phase kernel.
// Round-5: force MLP=9 in phase 1. Each pass issues zq + 8 zr gathers as
// volatile inline-asm global_load_dwordx4 (cannot be re-serialized by the
// scheduler), then one s_waitcnt vmcnt(0) asm whose "+v" operands DEFINE the
// 9 loaded values -- all consumers dataflow-depend on the waitcnt, so the
// hoist hazard (skill rule #18) cannot occur. Per-wave gather stalls drop
// from ~18 x latency (MLP~2) to 4 x latency (one drain per pass).
__global__ __launch_bounds__(256) void likelihood_kernel(
    const int* __restrict__ stim,     // N_TRIAL x 9
    const int* __restrict__ config,   // N_TRIAL
    const int* __restrict__ group,    // N_TRIAL
    const int* __restrict__ present,  // N_TRIAL x 9
    const float* __restrict__ embed,  // N_STIM x 16
    const float* __restrict__ attw,   // N_GROUP x 16
    float* __restrict__ out)          // N_TRIAL
{
    __shared__ int4  s_stim4[WPB][144];            // 64 trials x 9 ints, dense
    __shared__ float s_d2[WPB][N_REF][D2_STRIDE];  // [ref][trial] transpose

    const int tid  = threadIdx.x;
    const int wv   = tid >> 6;
    const int lane = tid & 63;
    const int q    = lane >> 2;   // quad id 0..15
    const int s    = lane & 3;    // float4 segment 0..3

    int wtb = blockIdx.x * 256 + wv * 64;          // this wave's 64 trials
    const bool valid = (wtb + lane) < N_TRIAL;
    if (wtb > N_TRIAL - 64) wtb = N_TRIAL - 64;    // N_TRIAL % 64 == 0

    // ---- dense coalesced staging of stim (16B-aligned: 64*9*4 = 2304) ----
    {
        const int4* g4 = (const int4*)(stim + wtb * 9);   // 144 int4 per wave
        s_stim4[wv][lane]      = g4[lane];
        s_stim4[wv][64 + lane] = g4[64 + lane];
        if (lane < 16) s_stim4[wv][128 + lane] = g4[128 + lane];
    }

    // ---- group ids for this lane's 4 quad-trials (4 VGPRs, issued early) --
    int gj[4];
#pragma unroll
    for (int j = 0; j < 4; ++j) gj[j] = group[wtb + 16 * j + q];

    const float* embed_s = embed + s * 4;          // this lane's row segment

    // ---------------- Phase 1: quad layout, 4 passes x 16 trials ----------
#pragma unroll
    for (int j = 0; j < 4; ++j) {
        const int* sp = (const int*)&s_stim4[wv][0] + (16 * j + q) * 9;
        int idx[9];
#pragma unroll
        for (int i = 0; i < 9; ++i) idx[i] = sp[i];   // conflict-free banks

        // attw: 256B table, L1-hot
        v4f w = *(const v4f*)(attw + gj[j] * N_DIM + s * 4);

        // ---- 9 gathers in flight, THEN one drain. volatile asm pins the
        //      issue order; the "+v" waitcnt below pins the consume point.
        v4f zq, z0, z1, z2, z3, z4, z5, z6, z7;
        ISSUE_GATHER(zq, embed_s + idx[0] * N_DIM);
        ISSUE_GATHER(z0, embed_s + idx[1] * N_DIM);
        ISSUE_GATHER(z1, embed_s + idx[2] * N_DIM);
        ISSUE_GATHER(z2, embed_s + idx[3] * N_DIM);
        ISSUE_GATHER(z3, embed_s + idx[4] * N_DIM);
        ISSUE_GATHER(z4, embed_s + idx[5] * N_DIM);
        ISSUE_GATHER(z5, embed_s + idx[6] * N_DIM);
        ISSUE_GATHER(z6, embed_s + idx[7] * N_DIM);
        ISSUE_GATHER(z7, embed_s + idx[8] * N_DIM);
        asm volatile("s_waitcnt vmcnt(0)"
                     : "+v"(zq), "+v"(z0), "+v"(z1), "+v"(z2), "+v"(z3),
                       "+v"(z4), "+v"(z5), "+v"(z6), "+v"(z7));

#define D2_OF(zr) ({ v4f dd_ = zq - (zr); v4f wd_ = w * dd_;             \
        quad_sum((wd_.x * dd_.x + wd_.y * dd_.y) +                       \
                 (wd_.z * dd_.z + wd_.w * dd_.w)); })
        float d2v0 = D2_OF(z0);
        float d2v1 = D2_OF(z1);
        float d2v2 = D2_OF(z2);
        float d2v3 = D2_OF(z3);
        float d2v4 = D2_OF(z4);
        float d2v5 = D2_OF(z5);
        float d2v6 = D2_OF(z6);
        float d2v7 = D2_OF(z7);
#undef D2_OF

        // lane s persists rows 2s, 2s+1 (uses the quad replication)
        float da = (s == 0) ? d2v0 : (s == 1) ? d2v2 : (s == 2) ? d2v4 : d2v6;
        float db = (s == 0) ? d2v1 : (s == 1) ? d2v3 : (s == 2) ? d2v5 : d2v7;
        s_d2[wv][2 * s    ][16 * j + q] = da;
        s_d2[wv][2 * s + 1][16 * j + q] = db;
    }
    // intra-wave ds_write -> ds_read ordering handled by compiler lgkmcnt;
    // no __syncthreads (all LDS state is per-wave).

    // ---------------- Phase 2: thread-per-trial tail -----------------------
    // Stream loads live here (after phase 1's register peak); their latency
    // is overlap-hidden by other resident waves' phase-1 compute.
    const int t2 = wtb + lane;                     // phase-2 trial (always valid addr)
    const int* pp = present + t2 * 9;
    v4iu p0 = *(const v4iu*)(pp + 1);              // present[1..4]
    v4iu p1 = *(const v4iu*)(pp + 5);              // present[5..8]
    int  c  = config[t2];

    int pr[N_REF] = {p0.x, p0.y, p0.z, p0.w, p1.x, p1.y, p1.z, p1.w};

    float sim[N_REF];
#pragma unroll
    for (int r = 0; r < N_REF; ++r) {
        float d2 = s_d2[wv][r][lane];
        sim[r] = (__expf(-BETA * sqrtf(d2)) + GAMMA) * (float)pr[r];
    }

    int ns = (N_SELECT_PACKED >> ((c & 3) * 4)) & 0xF;   // ns in {1,2,3}

    // only suffix[0..2] can be selected (max N_SELECT == 3)
    float suf2 = sim[7];
#pragma unroll
    for (int r = 6; r >= 2; --r) suf2 += sim[r];
    float suf1 = suf2 + sim[1];
    float suf0 = suf1 + sim[0];

    float num = sim[0] * ((ns >= 2) ? sim[1] : 1.0f) * ((ns >= 3) ? sim[2] : 1.0f);
    float den = suf0   * ((ns >= 2) ? suf1   : 1.0f) * ((ns >= 3) ? suf2   : 1.0f);

    if (valid)
        out[wtb + lane] = __fdividef(num, den);   // fully coalesced store
}

extern "C" void kernel_launch(void* const* d_in, const int* in_sizes, int n_in,
                              void* d_out, int out_size, void* d_ws, size_t ws_size,
                              hipStream_t stream) {
    const int*   stim    = (const int*)d_in[0];
    const int*   config  = (const int*)d_in[1];
    const int*   group   = (const int*)d_in[2];
    const int*   present = (const int*)d_in[3];
    const float* embed   = (const float*)d_in[4];
    const float* attw    = (const float*)d_in[5];
    float*       out     = (float*)d_out;

    int blocks = (N_TRIAL + 255) / 256;   // 3907; tail handled by clamp+valid
    likelihood_kernel<<<blocks, 256, 0, stream>>>(stim, config, group, present,
                                                  embed, attw, out);
}